// Round 4
// baseline (448.440 us; speedup 1.0000x reference)
//
#include <hip/hip_runtime.h>
#include <stdint.h>

#define NN 8192
#define DIM 128
#define ALPHA 0.2f
#define MTILE 32
#define BTHREADS 512          // 8 waves = 4 n-quarters x 2 k-halves
#define BK 256                // k-chunk per LDS tile
#define NCHUNK (NN / BK)      // 32
#define WSTRIDE (BK + 8)      // 528B row stride; 528/16=33 odd -> b128 conflict-free

typedef float f32x16 __attribute__((ext_vector_type(16)));
typedef short bf16x8 __attribute__((ext_vector_type(8)));

__device__ __forceinline__ float b2f(uint32_t u){
  uint32_t x = u << 16;
  float f;
  __builtin_memcpy(&f, &x, 4);
  return f;
}
__device__ __forceinline__ uint16_t f2b(float f){
  uint32_t x;
  __builtin_memcpy(&x, &f, 4);
  x += 0x7FFFu + ((x >> 16) & 1u);
  return (uint16_t)(x >> 16);
}

// Raw workgroup barrier: flush LDS ops (lgkm) but DO NOT drain vmcnt —
// staged global loads stay in flight across it (validated in round 3).
__device__ __forceinline__ void bar_lds(){
  asm volatile("s_waitcnt lgkmcnt(0)" ::: "memory");
  __builtin_amdgcn_s_barrier();
  asm volatile("" ::: "memory");
}

// Pure-stream: dist (268 MB fp32) -> bitmask (8 MB, byte b covers k=b*8+j, bit j).
// Runs in the fill-kernel regime: ~6.5 TB/s, ~43 us.
__global__ void __launch_bounds__(256)
mask_kernel(const float* __restrict__ dist, uint8_t* __restrict__ mask){
  const size_t nb = (size_t)NN * NN / 8;                 // 8M bytes
  const size_t stride = (size_t)gridDim.x * 256;
  for (size_t f = (size_t)blockIdx.x * 256 + threadIdx.x; f < nb; f += stride){
    const float* p = dist + f * 8;
    float4 a = *(const float4*)(p);
    float4 b = *(const float4*)(p + 4);
    uint32_t m = 0;
    m |= (a.x < 0.5f) ? 1u   : 0u;
    m |= (a.y < 0.5f) ? 2u   : 0u;
    m |= (a.z < 0.5f) ? 4u   : 0u;
    m |= (a.w < 0.5f) ? 8u   : 0u;
    m |= (b.x < 0.5f) ? 16u  : 0u;
    m |= (b.y < 0.5f) ? 32u  : 0u;
    m |= (b.z < 0.5f) ? 64u  : 0u;
    m |= (b.w < 0.5f) ? 128u : 0u;
    mask[f] = (uint8_t)m;
  }
}

// s1[i] = nodes[i,:] . a[0:128], s2[i] = nodes[i,:] . a[128:256]  (all fp32)
__global__ void s_kernel(const float* __restrict__ nodes,
                         const float* __restrict__ a,
                         float* __restrict__ s1, float* __restrict__ s2){
  int row  = blockIdx.x * 4 + (threadIdx.x >> 6);
  int lane = threadIdx.x & 63;
  float2 nv  = *(const float2*)(nodes + row * DIM + lane * 2);
  float2 a1v = *(const float2*)(a + lane * 2);
  float2 a2v = *(const float2*)(a + DIM + lane * 2);
  float p1 = nv.x * a1v.x + nv.y * a1v.y;
  float p2 = nv.x * a2v.x + nv.y * a2v.y;
  #pragma unroll
  for (int off = 32; off; off >>= 1){
    p1 += __shfl_down(p1, off);
    p2 += __shfl_down(p2, off);
  }
  if (lane == 0){ s1[row] = p1; s2[row] = p2; }
}

// nodesT[n][k] = bf16(nodes[k][n])
__global__ void t_kernel(const float* __restrict__ nodes,
                         uint16_t* __restrict__ nodesT){
  __shared__ uint16_t tile[32][33];
  int kb = blockIdx.x * 32, nb = blockIdx.y * 32;
  int tx = threadIdx.x & 31, ty = threadIdx.x >> 5;
  for (int r = ty; r < 32; r += 8)
    tile[r][tx] = f2b(nodes[(size_t)(kb + r) * DIM + nb + tx]);
  __syncthreads();
  for (int r = ty; r < 32; r += 8)
    nodesT[(size_t)(nb + r) * NN + kb + tx] = tile[tx][r];
}

// Fused GAT row-block, round-0 structure; dist stream replaced by the 8 MB
// bitmask (2 bytes/thread/chunk) -> compute/L2-bound, barrier drain harmless.
__global__ void __launch_bounds__(BTHREADS, 4)
attn_kernel(const uint8_t* __restrict__ mask,
            const uint16_t* __restrict__ nodesT,
            const float* __restrict__ s1,
            const float* __restrict__ s2,
            float* __restrict__ out){
  __shared__ uint16_t Wbuf[2][MTILE][WSTRIDE];   // 33.8 KB
  __shared__ float accT[MTILE][DIM];             // 16 KB
  __shared__ float denT[MTILE];

  const int tid  = threadIdx.x;
  const int lane = tid & 63;
  const int wave = tid >> 6;
  const int i0   = blockIdx.x * MTILE;

  // ---- W-gen mapping: thread -> (row, 16 k's split as wr*8 + {0,128}) ----
  const int wrow = tid >> 4;          // 0..31
  const int wr   = tid & 15;          // 0..15
  const float s1v = s1[i0 + wrow];
  const uint8_t* mRow = mask + (size_t)(i0 + wrow) * (NN / 8) + wr;

  // ---- MFMA mapping: wave -> (n-quarter q, k-half h) ----
  const int q    = wave & 3;
  const int h    = wave >> 2;
  const int m    = lane & 31;
  const int half = lane >> 5;
  const uint16_t* bRow = nodesT + (size_t)(q * 32 + m) * NN;

  f32x16 acc;
  #pragma unroll
  for (int i = 0; i < 16; i++) acc[i] = 0.f;
  float den = 0.f;

  uint32_t mb0, mb1;                  // staged mask bytes
  float4 ps0, ps1, ps2, ps3;          // staged s2 (L2-hot)

  auto load_chunk = [&](int s){
    mb0 = mRow[s * 32];               // k = s*256 + wr*8 .. +8
    mb1 = mRow[s * 32 + 16];          // k = s*256 + 128 + wr*8 .. +8
    const float* spp = s2 + s * BK + wr * 8;
    ps0 = *(const float4*)(spp);
    ps1 = *(const float4*)(spp + 4);
    ps2 = *(const float4*)(spp + 128);
    ps3 = *(const float4*)(spp + 132);
  };

  auto gen_write = [&](int buf){
    float sv[16] = {ps0.x, ps0.y, ps0.z, ps0.w, ps1.x, ps1.y, ps1.z, ps1.w,
                    ps2.x, ps2.y, ps2.z, ps2.w, ps3.x, ps3.y, ps3.z, ps3.w};
    union { bf16x8 v; uint16_t u[8]; } w0, w1;
    #pragma unroll
    for (int j = 0; j < 8; j++){
      float x = s1v + sv[j];
      float e = fmaxf(x, ALPHA * x);
      float w = ((mb0 >> j) & 1u) ? __expf(e) : 0.f;
      uint16_t wq = f2b(w);
      w0.u[j] = wq;
      den += b2f((uint32_t)wq);       // denominator sees the SAME quantized W
    }
    #pragma unroll
    for (int j = 0; j < 8; j++){
      float x = s1v + sv[8 + j];
      float e = fmaxf(x, ALPHA * x);
      float w = ((mb1 >> j) & 1u) ? __expf(e) : 0.f;
      uint16_t wq = f2b(w);
      w1.u[j] = wq;
      den += b2f((uint32_t)wq);
    }
    *(bf16x8*)&Wbuf[buf][wrow][wr * 8]       = w0.v;
    *(bf16x8*)&Wbuf[buf][wrow][wr * 8 + 128] = w1.v;
  };

  // Prologue: chunk 0 into buf 0.
  load_chunk(0);
  gen_write(0);

  for (int s = 0; s < NCHUNK; s++){
    if (s + 1 < NCHUNK) load_chunk(s + 1);   // tiny prefetch, survives bar_lds
    bar_lds();
    const int buf = s & 1;
    const size_t kb = (size_t)s * BK;
    bf16x8 bvv[8];
    #pragma unroll
    for (int kk = 0; kk < 8; kk++)
      bvv[kk] = *(const bf16x8*)(bRow + kb + h * 128 + kk * 16 + half * 8);
    #pragma unroll
    for (int kk = 0; kk < 8; kk++){
      int ko = h * 128 + kk * 16 + half * 8;
      bf16x8 av = *(const bf16x8*)&Wbuf[buf][m][ko];
      acc = __builtin_amdgcn_mfma_f32_32x32x16_bf16(av, bvv[kk], acc, 0, 0, 0);
    }
    if (s + 1 < NCHUNK) gen_write((s + 1) & 1);
  }

  // ---- denominator: 16 threads per row, all in one wave -> shfl reduce ----
  den += __shfl_down(den, 8, 16);
  den += __shfl_down(den, 4, 16);
  den += __shfl_down(den, 2, 16);
  den += __shfl_down(den, 1, 16);
  if (wr == 0) denT[wrow] = 1.0f / den;

  // ---- combine k-half pairs via LDS, normalize, store fp32 ----
  if (h == 0){
    #pragma unroll
    for (int r = 0; r < 16; r++){
      int row = (r & 3) + 8 * (r >> 2) + 4 * half;
      accT[row][q * 32 + m] = acc[r];
    }
  }
  __syncthreads();
  if (h == 1){
    #pragma unroll
    for (int r = 0; r < 16; r++){
      int row = (r & 3) + 8 * (r >> 2) + 4 * half;
      float v = (accT[row][q * 32 + m] + acc[r]) * denT[row];
      out[(size_t)(i0 + row) * DIM + q * 32 + m] = v;
    }
  }
}

extern "C" void kernel_launch(void* const* d_in, const int* in_sizes, int n_in,
                              void* d_out, int out_size, void* d_ws, size_t ws_size,
                              hipStream_t stream){
  const float* nodes = (const float*)d_in[0];
  const float* dist  = (const float*)d_in[1];
  const float* a     = (const float*)d_in[2];
  float* out = (float*)d_out;

  char* ws = (char*)d_ws;
  float*    s1     = (float*)ws;                          // 32 KB
  float*    s2     = (float*)(ws + (32 << 10));           // 32 KB
  uint16_t* nodesT = (uint16_t*)(ws + (64 << 10));        // 2 MB
  uint8_t*  mask   = (uint8_t*)(ws + (64 << 10) + (NN * NN / 4)); // 8 MB

  mask_kernel<<<2048, 256, 0, stream>>>(dist, mask);
  s_kernel<<<NN / 4, 256, 0, stream>>>(nodes, a, s1, s2);
  t_kernel<<<dim3(NN / 32, DIM / 32), 256, 0, stream>>>(nodes, nodesT);
  attn_kernel<<<NN / MTILE, BTHREADS, 0, stream>>>(mask, nodesT, s1, s2, out);
}